// Round 9
// baseline (2656.041 us; speedup 1.0000x reference)
//
#include <hip/hip_runtime.h>
#include <hip/hip_bf16.h>

#define T_STEPS 64
#define B_DIM 2048
#define U_DIM 1024

#define BM 128
#define BU 32
#define NSTAGES 8        // K stages of 128
#define KT_TOTAL 32      // K iters of 32

typedef __attribute__((ext_vector_type(8))) _Float16 h8;
typedef __attribute__((ext_vector_type(4))) float f4;

__device__ __forceinline__ void async_cp16(const _Float16* g, _Float16* l) {
    __builtin_amdgcn_global_load_lds((const __attribute__((address_space(1))) void*)g,
                                     (__attribute__((address_space(3))) void*)l,
                                     16, 0, 0);
}

// ---------------- init kernels ----------------

// R: [U][2U] f32 row-major -> Rt: [2U][U] f16 (B^T layout)
__global__ void transpose_R(const float* __restrict__ R, _Float16* __restrict__ Rt) {
    __shared__ float tile[32][33];
    int nb = blockIdx.x * 32;
    int kb = blockIdx.y * 32;
    int tx = threadIdx.x, ty = threadIdx.y;   // block (32,8)
    #pragma unroll
    for (int i = ty; i < 32; i += 8)
        tile[i][tx] = R[(size_t)(kb + i) * (2 * U_DIM) + nb + tx];
    __syncthreads();
    #pragma unroll
    for (int i = ty; i < 32; i += 8)
        Rt[(size_t)(nb + i) * U_DIM + kb + tx] = (_Float16)tile[tx][i];
}

__global__ void init_state(const float* __restrict__ c0, _Float16* __restrict__ h0,
                           float* __restrict__ y) {
    int i = blockIdx.x * 256 + threadIdx.x;
    h0[i] = (_Float16)c0[i];
    if (i < 3 * B_DIM) y[i] = 0.f;
}

// ---------------- per-step fused kernel ----------------
// 2 blocks/CU (8 waves). A-frags: global->VGPR reg-dbuf. B-frags: 2-stage
// 16KB LDS DMA with XOR swizzle. Epilogue h-read/c-write direct global.
__global__ __launch_bounds__(256, 2) void gemm_step(
    const _Float16* __restrict__ hA, _Float16* __restrict__ hB,
    const _Float16* __restrict__ Rt,
    const float* __restrict__ x1_0, const float* __restrict__ x2_0,
    float* __restrict__ x1w,          // [2][B]
    float* __restrict__ x2w,          // [2][B]
    const float* __restrict__ kern, const float* __restrict__ bias,
    const float* __restrict__ okern,
    float* __restrict__ y,            // [3][B]
    const float* __restrict__ inputs, // [T][B]
    float* __restrict__ out,          // [T][B]
    int t)
{
    __shared__ __align__(16) _Float16 lB[2][2][4096];  // [stage][f/c][8 reg x 512] = 32 KB
    __shared__ float x1s[BM];

    const int tid    = threadIdx.x;
    const int wid    = tid >> 6;
    const int lane   = tid & 63;
    const int lane15 = lane & 15;
    const int quad   = lane >> 4;

    // per-XCD 4u x 16b rectangle (XCD heuristic: blk % 8)
    const int lin  = blockIdx.x;
    const int g    = lin & 7;
    const int ii   = lin >> 3;                  // 0..63
    const int bblk = (g & 3) * 4 + (ii & 3);    // 0..15
    const int ublk = (g >> 2) * 16 + (ii >> 2); // 0..31
    const int b0   = bblk * BM;
    const int u0   = ublk * BU;

    const int wrow = (wid >> 1) * 64;   // 0 / 64
    const int wcol = (wid & 1) * 16;    // 0 / 16

    // ---- B stage DMA (16 KB: Rf 8K + Rc 8K), XOR-swizzled slots ----
    auto stage = [&](int buf, int s) {
        const int sK = s * 128;
        #pragma unroll
        for (int j = 0; j < 4; ++j) {
            const int idx = wid * 4 + j;       // 0..15
            const int hf  = idx >> 3;
            const int rg  = idx & 7;           // region: 4 u-rows x 16 chunks
            const int row = rg * 4 + (lane & 3);
            const int ch  = ((lane >> 2) ^ (lane & 3) ^ rg) & 15;
            const _Float16* gp = Rt + (size_t)(hf * U_DIM + u0 + row) * U_DIM + sK + ch * 8;
            async_cp16(gp, &lB[buf][hf][rg * 512]);
        }
    };
    stage(0, 0);

    // ---- prologue: integrator state for this step ----
    if (tid < BM) {
        const int b = b0 + tid;
        float x1n, x2n;
        if (t == 0) {
            x1n = x1_0[b];
            x2n = x2_0[b];
        } else {
            const int rd = (t + 1) & 1;
            const float x1p = x1w[rd * B_DIM + b];
            const float x2p = x2w[rd * B_DIM + b];
            const float yp  = y[((t + 2) % 3) * B_DIM + b];
            const float ip  = inputs[(size_t)(t - 1) * B_DIM + b];
            x1n = x1p + x2p;
            x2n = x2p + ip * yp;
        }
        x1s[tid] = x1n;
        if (ublk == 0) {
            const int wr = t & 1;
            x1w[wr * B_DIM + b] = x1n;
            x2w[wr * B_DIM + b] = x2n;
            if (t > 0) out[(size_t)(t - 1) * B_DIM + b] = x1n;
            y[((t + 1) % 3) * B_DIM + b] = 0.f;
        }
    }

    // ---- epilogue constants + h prefetch (L2 sector-aligned 32B rows) ----
    const int u = u0 + wcol + lane15;
    const float kf  = kern[u];
    const float kc  = kern[U_DIM + u];
    const float bfv = bias[u];
    const float bcv = bias[U_DIM + u];
    const float okr = okern[u];

    _Float16 hv[4][4];
    #pragma unroll
    for (int mt = 0; mt < 4; ++mt)
        #pragma unroll
        for (int reg = 0; reg < 4; ++reg)
            hv[mt][reg] = hA[(size_t)(b0 + wrow + mt * 16 + quad * 4 + reg) * U_DIM + u];

    // ---- A pointers + first fragment preload ----
    const _Float16* aptr[4];
    #pragma unroll
    for (int mt = 0; mt < 4; ++mt)
        aptr[mt] = hA + (size_t)(b0 + wrow + mt * 16 + lane15) * U_DIM;

    h8 a[2][4];
    #pragma unroll
    for (int mt = 0; mt < 4; ++mt)
        a[0][mt] = *(const h8*)&aptr[mt][quad * 8];

    f4 accF[4], accC[4];
    #pragma unroll
    for (int mt = 0; mt < 4; ++mt) {
        accF[mt] = (f4){0.f, 0.f, 0.f, 0.f};
        accC[mt] = (f4){0.f, 0.f, 0.f, 0.f};
    }

    // B-frag read indexing (inverse of stage swizzle)
    const int brow = wcol + lane15;            // 0..31
    const int b_i  = brow >> 2;
    const int b_b  = brow & 3;
    const int xorb = b_b ^ b_i;
    const int boff = b_i * 512 + b_b * 8;

    // ---- K-loop: 8 stages x 4 kt ----
    for (int s = 0; s < NSTAGES; ++s) {
        __syncthreads();                        // stage s DMA complete; buf reuse safe
        if (s + 1 < NSTAGES) stage((s + 1) & 1, s + 1);
        #pragma unroll
        for (int ktl = 0; ktl < 4; ++ktl) {
            const int ktg = s * 4 + ktl;
            if (ktg + 1 < KT_TOTAL) {
                const int koff = (ktg + 1) * 32 + quad * 8;
                #pragma unroll
                for (int mt = 0; mt < 4; ++mt)
                    a[(ktg + 1) & 1][mt] = *(const h8*)&aptr[mt][koff];
            }
            const int c = ktl * 4 + quad;
            const h8 bf = *(const h8*)&lB[s & 1][0][boff + ((c ^ xorb) << 5)];
            const h8 bc = *(const h8*)&lB[s & 1][1][boff + ((c ^ xorb) << 5)];
            #pragma unroll
            for (int mt = 0; mt < 4; ++mt) {
                accF[mt] = __builtin_amdgcn_mfma_f32_16x16x32_f16(a[ktg & 1][mt], bf, accF[mt], 0, 0, 0);
                accC[mt] = __builtin_amdgcn_mfma_f32_16x16x32_f16(a[ktg & 1][mt], bc, accC[mt], 0, 0, 0);
            }
        }
    }

    // ---- epilogue: gates, direct c store, y partials ----
    float* ycur = y + (t % 3) * B_DIM;
    #pragma unroll
    for (int mt = 0; mt < 4; ++mt) {
        float psum[4];
        #pragma unroll
        for (int reg = 0; reg < 4; ++reg) {
            const int rl = wrow + mt * 16 + quad * 4 + reg;
            const float x1 = x1s[rl];
            const float xf = accF[mt][reg] + x1 * kf + bfv;
            const float xc = accC[mt][reg] + x1 * kc + bcv;
            const float fg = 1.f / (1.f + __expf(-xf));
            const float th = 1.f - 2.f / (1.f + __expf(2.f * xc));
            const float cv = fg * (float)hv[mt][reg] + (1.f - fg) * th;
            hB[(size_t)(b0 + rl) * U_DIM + u] = (_Float16)cv;
            psum[reg] = cv * okr;
        }
        #pragma unroll
        for (int reg = 0; reg < 4; ++reg) {
            float sgm = psum[reg];
            sgm += __shfl_xor(sgm, 1);
            sgm += __shfl_xor(sgm, 2);
            sgm += __shfl_xor(sgm, 4);
            sgm += __shfl_xor(sgm, 8);
            if (lane15 == 0)
                atomicAdd(&ycur[b0 + wrow + mt * 16 + quad * 4 + reg], sgm);
        }
    }
}

// ---------------- tail: out[T-1] = x1(T) ----------------
__global__ void finish(const float* __restrict__ x1w1, const float* __restrict__ x2w1,
                       float* __restrict__ out_last) {
    const int i = blockIdx.x * 256 + threadIdx.x;
    out_last[i] = x1w1[i] + x2w1[i];
}

// ---------------- host ----------------
extern "C" void kernel_launch(void* const* d_in, const int* in_sizes, int n_in,
                              void* d_out, int out_size, void* d_ws, size_t ws_size,
                              hipStream_t stream) {
    const float* inputs = (const float*)d_in[0];
    const float* x1_0   = (const float*)d_in[1];
    const float* x2_0   = (const float*)d_in[2];
    const float* c0     = (const float*)d_in[3];
    const float* kern   = (const float*)d_in[4];
    const float* rker   = (const float*)d_in[5];
    const float* bias   = (const float*)d_in[6];
    const float* okern  = (const float*)d_in[7];
    float* out = (float*)d_out;

    _Float16* Rt = (_Float16*)d_ws;                       // 4 MB
    _Float16* h0 = Rt + (size_t)2 * U_DIM * U_DIM;        // 4 MB
    _Float16* h1 = h0 + (size_t)B_DIM * U_DIM;            // 4 MB
    float* y   = (float*)(h1 + (size_t)B_DIM * U_DIM);    // 3*B
    float* x1w = y + 3 * B_DIM;                           // 2*B
    float* x2w = x1w + 2 * B_DIM;                         // 2*B

    transpose_R<<<dim3(64, 32), dim3(32, 8), 0, stream>>>(rker, Rt);
    init_state<<<dim3(B_DIM * U_DIM / 256), dim3(256), 0, stream>>>(c0, h0, y);

    _Float16* hcur = h0;
    _Float16* hnxt = h1;
    for (int t = 0; t < T_STEPS; ++t) {
        gemm_step<<<dim3(512), dim3(256), 0, stream>>>(
            hcur, hnxt, Rt, x1_0, x2_0, x1w, x2w, kern, bias, okern, y,
            inputs, out, t);
        _Float16* tmp = hcur; hcur = hnxt; hnxt = tmp;
    }
    finish<<<dim3(B_DIM / 256), dim3(256), 0, stream>>>(
        x1w + B_DIM, x2w + B_DIM, out + (size_t)(T_STEPS - 1) * B_DIM);
}

// Round 10
// 1535.533 us; speedup vs baseline: 1.7297x; 1.7297x over previous
//
#include <hip/hip_runtime.h>
#include <hip/hip_bf16.h>

#define T_STEPS 64
#define B_DIM 2048
#define U_DIM 1024

#define BM 128
#define BU 64
#define BK 32
#define KITERS (U_DIM / BK)   // 32
#define NST 3
#define STG 8192              // halfs per stage (16 KB): A 4096 + Bf 2048 + Bc 2048

typedef __attribute__((ext_vector_type(8))) _Float16 h8;
typedef __attribute__((ext_vector_type(4))) float f4;

__device__ __forceinline__ void async_cp16(const _Float16* g, _Float16* l) {
    __builtin_amdgcn_global_load_lds((const __attribute__((address_space(1))) void*)g,
                                     (__attribute__((address_space(3))) void*)l,
                                     16, 0, 0);
}

// ---------------- init kernels ----------------

// R: [U][2U] f32 row-major -> Rt: [2U][U] f16 (B^T layout)
__global__ void transpose_R(const float* __restrict__ R, _Float16* __restrict__ Rt) {
    __shared__ float tile[32][33];
    int nb = blockIdx.x * 32;
    int kb = blockIdx.y * 32;
    int tx = threadIdx.x, ty = threadIdx.y;   // block (32,8)
    #pragma unroll
    for (int i = ty; i < 32; i += 8)
        tile[i][tx] = R[(size_t)(kb + i) * (2 * U_DIM) + nb + tx];
    __syncthreads();
    #pragma unroll
    for (int i = ty; i < 32; i += 8)
        Rt[(size_t)(nb + i) * U_DIM + kb + tx] = (_Float16)tile[tx][i];
}

__global__ void init_state(const float* __restrict__ c0, _Float16* __restrict__ h0,
                           float* __restrict__ y) {
    int i = blockIdx.x * 256 + threadIdx.x;
    h0[i] = (_Float16)c0[i];
    if (i < 3 * B_DIM) y[i] = 0.f;
}

// ---------------- per-step fused kernel ----------------
// R6 pipeline, compacted: BK=32, 3 x 16KB stages (48.5 KB LDS total) -> ~3
// blocks/CU so barrier/vmcnt drains of one block overlap compute of others.
// h for gating prefetched to registers; lC overlays stage memory.
__global__ __launch_bounds__(256, 2) void gemm_step(
    const _Float16* __restrict__ hA, _Float16* __restrict__ hB,
    const _Float16* __restrict__ Rt,
    const float* __restrict__ x1_0, const float* __restrict__ x2_0,
    float* __restrict__ x1w,          // [2][B]
    float* __restrict__ x2w,          // [2][B]
    const float* __restrict__ kern, const float* __restrict__ bias,
    const float* __restrict__ okern,
    float* __restrict__ y,            // [3][B]
    const float* __restrict__ inputs, // [T][B]
    float* __restrict__ out,          // [T][B]
    int t)
{
    __shared__ __align__(16) _Float16 lS[NST][STG];   // 48 KB (stages; lC overlays)
    __shared__ float x1s[BM];

    const int tid    = threadIdx.x;
    const int wid    = tid >> 6;
    const int lane   = tid & 63;
    const int lane15 = lane & 15;
    const int quad   = lane >> 4;
    const int u0     = blockIdx.x * BU;
    const int b0     = blockIdx.y * BM;
    const int wrow   = (wid >> 1) * 64;
    const int wcol   = (wid & 1) * 32;

    // ---- prologue: integrator state (pure loads issued first) ----
    if (tid < BM) {
        const int b = b0 + tid;
        float x1n, x2n;
        if (t == 0) {
            x1n = x1_0[b];
            x2n = x2_0[b];
        } else {
            const int rd = (t + 1) & 1;
            const float x1p = x1w[rd * B_DIM + b];
            const float x2p = x2w[rd * B_DIM + b];
            const float yp  = y[((t + 2) % 3) * B_DIM + b];
            const float ip  = inputs[(size_t)(t - 1) * B_DIM + b];
            x1n = x1p + x2p;
            x2n = x2p + ip * yp;
        }
        x1s[tid] = x1n;
        if (blockIdx.x == 0) {
            const int wr = t & 1;
            x1w[wr * B_DIM + b] = x1n;
            x2w[wr * B_DIM + b] = x2n;
            if (t > 0) out[(size_t)(t - 1) * B_DIM + b] = x1n;
            y[((t + 1) % 3) * B_DIM + b] = 0.f;
        }
    }

    // ---- epilogue constants + h-register prefetch (before stage DMAs) ----
    float kf[2], kc[2], bf_[2], bc_[2], ok_[2];
    #pragma unroll
    for (int nt = 0; nt < 2; ++nt) {
        const int u = u0 + wcol + nt * 16 + lane15;
        kf[nt] = kern[u];
        kc[nt] = kern[U_DIM + u];
        bf_[nt] = bias[u];
        bc_[nt] = bias[U_DIM + u];
        ok_[nt] = okern[u];
    }
    _Float16 hv[4][2][4];
    #pragma unroll
    for (int mt = 0; mt < 4; ++mt)
        #pragma unroll
        for (int nt = 0; nt < 2; ++nt)
            #pragma unroll
            for (int reg = 0; reg < 4; ++reg)
                hv[mt][nt][reg] = hA[(size_t)(b0 + wrow + mt * 16 + quad * 4 + reg) * U_DIM
                                     + u0 + wcol + nt * 16 + lane15];

    // ---- stage DMA: 16 regions of 1 KB (A: 8, Bf: 4, Bc: 4), 4/wave ----
    // region = 16 rows x 4 chunks; lane l -> row l>>2, src chunk (l&3)^((l>>2)&3)
    const int srow  = lane >> 2;
    const int schnk = ((lane & 3) ^ (srow & 3)) * 8;
    auto stage = [&](int buf, int kt) {
        const int k0 = kt * BK;
        #pragma unroll
        for (int j = 0; j < 2; ++j) {
            const int r = wid * 2 + j;   // A region 0..7
            async_cp16(hA + (size_t)(b0 + r * 16 + srow) * U_DIM + k0 + schnk,
                       &lS[buf][r * 512]);
        }
        async_cp16(Rt + (size_t)(u0 + wid * 16 + srow) * U_DIM + k0 + schnk,
                   &lS[buf][4096 + wid * 512]);
        async_cp16(Rt + (size_t)(U_DIM + u0 + wid * 16 + srow) * U_DIM + k0 + schnk,
                   &lS[buf][6144 + wid * 512]);
    };
    stage(0, 0);
    stage(1, 1);

    f4 accF[4][2], accC[4][2];
    #pragma unroll
    for (int mt = 0; mt < 4; ++mt)
        #pragma unroll
        for (int nt = 0; nt < 2; ++nt) {
            accF[mt][nt] = (f4){0.f, 0.f, 0.f, 0.f};
            accC[mt][nt] = (f4){0.f, 0.f, 0.f, 0.f};
        }

    // ---- 3-stage pipelined K-loop (4 DMAs/wave/stage -> vmcnt(4)) ----
    for (int kt = 0; kt < KITERS; ++kt) {
        const int cur = kt % 3;
        if (kt < KITERS - 1)
            __builtin_amdgcn_s_waitcnt(0x0F74);   // vmcnt(4): stage kt done
        else
            __builtin_amdgcn_s_waitcnt(0x0F70);   // vmcnt(0)
        __syncthreads();
        if (kt + 2 < KITERS) stage((kt + 2) % 3, kt + 2);

        h8 af[4], bff[2], bfc[2];
        #pragma unroll
        for (int mt = 0; mt < 4; ++mt) {
            const int R = wrow + mt * 16 + lane15;
            af[mt] = *(const h8*)&lS[cur][(R >> 4) * 512 + lane15 * 32 +
                                          ((quad ^ (lane15 & 3)) * 8)];
        }
        #pragma unroll
        for (int nt = 0; nt < 2; ++nt) {
            const int Rb = wcol + nt * 16 + lane15;
            const int off = (Rb >> 4) * 512 + lane15 * 32 + ((quad ^ (lane15 & 3)) * 8);
            bff[nt] = *(const h8*)&lS[cur][4096 + off];
            bfc[nt] = *(const h8*)&lS[cur][6144 + off];
        }
        #pragma unroll
        for (int mt = 0; mt < 4; ++mt)
            #pragma unroll
            for (int nt = 0; nt < 2; ++nt) {
                accF[mt][nt] = __builtin_amdgcn_mfma_f32_16x16x32_f16(af[mt], bff[nt], accF[mt][nt], 0, 0, 0);
                accC[mt][nt] = __builtin_amdgcn_mfma_f32_16x16x32_f16(af[mt], bfc[nt], accC[mt][nt], 0, 0, 0);
            }
    }

    __syncthreads();   // all waves done with stage buffers; lC overlay safe

    // ---- epilogue: gates (h from regs); c -> lC; y partials ----
    _Float16* lC = &lS[0][0];   // 128 x 72 halfs = 18 KB
    float* ycur = y + (t % 3) * B_DIM;
    #pragma unroll
    for (int mt = 0; mt < 4; ++mt) {
        const int rlb = wrow + mt * 16 + quad * 4;
        float psum[4] = {0.f, 0.f, 0.f, 0.f};
        #pragma unroll
        for (int nt = 0; nt < 2; ++nt) {
            const int ul = wcol + nt * 16 + lane15;
            #pragma unroll
            for (int reg = 0; reg < 4; ++reg) {
                const int rl = rlb + reg;
                const float x1 = x1s[rl];
                const float xf = accF[mt][nt][reg] + x1 * kf[nt] + bf_[nt];
                const float xc = accC[mt][nt][reg] + x1 * kc[nt] + bc_[nt];
                const float fg = 1.f / (1.f + __expf(-xf));
                const float th = 1.f - 2.f / (1.f + __expf(2.f * xc));
                const float cv = fg * (float)hv[mt][nt][reg] + (1.f - fg) * th;
                lC[rl * 72 + ul] = (_Float16)cv;
                psum[reg] += cv * ok_[nt];
            }
        }
        #pragma unroll
        for (int reg = 0; reg < 4; ++reg) {
            float s = psum[reg];
            s += __shfl_xor(s, 1);
            s += __shfl_xor(s, 2);
            s += __shfl_xor(s, 4);
            s += __shfl_xor(s, 8);
            if (lane15 == 0) atomicAdd(&ycur[b0 + rlb + reg], s);
        }
    }

    // ---- coalesced c write-out ----
    __syncthreads();
    #pragma unroll
    for (int j = 0; j < 4; ++j) {
        const int idx = j * 256 + tid;     // 1024 uint4 = 128 rows x 8
        const int row = idx >> 3;
        const int col = idx & 7;
        *(uint4*)&hB[(size_t)(b0 + row) * U_DIM + u0 + col * 8] =
            *(const uint4*)&lC[row * 72 + col * 8];
    }
}

// ---------------- tail: out[T-1] = x1(T) ----------------
__global__ void finish(const float* __restrict__ x1w1, const float* __restrict__ x2w1,
                       float* __restrict__ out_last) {
    const int i = blockIdx.x * 256 + threadIdx.x;
    out_last[i] = x1w1[i] + x2w1[i];
}

// ---------------- host ----------------
extern "C" void kernel_launch(void* const* d_in, const int* in_sizes, int n_in,
                              void* d_out, int out_size, void* d_ws, size_t ws_size,
                              hipStream_t stream) {
    const float* inputs = (const float*)d_in[0];
    const float* x1_0   = (const float*)d_in[1];
    const float* x2_0   = (const float*)d_in[2];
    const float* c0     = (const float*)d_in[3];
    const float* kern   = (const float*)d_in[4];
    const float* rker   = (const float*)d_in[5];
    const float* bias   = (const float*)d_in[6];
    const float* okern  = (const float*)d_in[7];
    float* out = (float*)d_out;

    _Float16* Rt = (_Float16*)d_ws;                       // 4 MB
    _Float16* h0 = Rt + (size_t)2 * U_DIM * U_DIM;        // 4 MB
    _Float16* h1 = h0 + (size_t)B_DIM * U_DIM;            // 4 MB
    float* y   = (float*)(h1 + (size_t)B_DIM * U_DIM);    // 3*B
    float* x1w = y + 3 * B_DIM;                           // 2*B
    float* x2w = x1w + 2 * B_DIM;                         // 2*B

    transpose_R<<<dim3(64, 32), dim3(32, 8), 0, stream>>>(rker, Rt);
    init_state<<<dim3(B_DIM * U_DIM / 256), dim3(256), 0, stream>>>(c0, h0, y);

    _Float16* hcur = h0;
    _Float16* hnxt = h1;
    for (int t = 0; t < T_STEPS; ++t) {
        gemm_step<<<dim3(U_DIM / BU, B_DIM / BM), dim3(256), 0, stream>>>(
            hcur, hnxt, Rt, x1_0, x2_0, x1w, x2w, kern, bias, okern, y,
            inputs, out, t);
        _Float16* tmp = hcur; hcur = hnxt; hnxt = tmp;
    }
    finish<<<dim3(B_DIM / 256), dim3(256), 0, stream>>>(
        x1w + B_DIM, x2w + B_DIM, out + (size_t)(T_STEPS - 1) * B_DIM);
}

// Round 11
// 1528.848 us; speedup vs baseline: 1.7373x; 1.0044x over previous
//
#include <hip/hip_runtime.h>
#include <hip/hip_bf16.h>

#define T_STEPS 64
#define B_DIM 2048
#define U_DIM 1024

#define BM 128
#define BU 64
#define BK 32
#define KITERS (U_DIM / BK)   // 32
#define NSTG 4                // per-wave rotating stage buffers

typedef __attribute__((ext_vector_type(8))) _Float16 h8;
typedef __attribute__((ext_vector_type(4))) float f4;

__device__ __forceinline__ void async_cp16(const _Float16* g, _Float16* l) {
    __builtin_amdgcn_global_load_lds((const __attribute__((address_space(1))) void*)g,
                                     (__attribute__((address_space(3))) void*)l,
                                     16, 0, 0);
}

// ---------------- init kernels ----------------

// R: [U][2U] f32 row-major -> Rt: [2U][U] f16 (B^T layout)
__global__ void transpose_R(const float* __restrict__ R, _Float16* __restrict__ Rt) {
    __shared__ float tile[32][33];
    int nb = blockIdx.x * 32;
    int kb = blockIdx.y * 32;
    int tx = threadIdx.x, ty = threadIdx.y;   // block (32,8)
    #pragma unroll
    for (int i = ty; i < 32; i += 8)
        tile[i][tx] = R[(size_t)(kb + i) * (2 * U_DIM) + nb + tx];
    __syncthreads();
    #pragma unroll
    for (int i = ty; i < 32; i += 8)
        Rt[(size_t)(nb + i) * U_DIM + kb + tx] = (_Float16)tile[tx][i];
}

__global__ void init_state(const float* __restrict__ c0, _Float16* __restrict__ h0,
                           float* __restrict__ y) {
    int i = blockIdx.x * 256 + threadIdx.x;
    h0[i] = (_Float16)c0[i];
    if (i < 3 * B_DIM) y[i] = 0.f;
}

// ---------------- per-step fused kernel ----------------
// Shared-nothing waves: each wave stages its own A-rows (64) + B-cols (32, f&c)
// into a private 4-stage LDS ring. NO barriers in the K-loop; each wave
// self-paces on vmcnt. Waves drift out of phase -> MFMA/LDS/VMEM overlap.
__global__ __launch_bounds__(256, 1) void gemm_step(
    const _Float16* __restrict__ hA, _Float16* __restrict__ hB,
    const _Float16* __restrict__ Rt,
    const float* __restrict__ x1_0, const float* __restrict__ x2_0,
    float* __restrict__ x1w,          // [2][B]
    float* __restrict__ x2w,          // [2][B]
    const float* __restrict__ kern, const float* __restrict__ bias,
    const float* __restrict__ okern,
    float* __restrict__ y,            // [3][B]
    const float* __restrict__ inputs, // [T][B]
    float* __restrict__ out,          // [T][B]
    int t)
{
    // [wave][stage][ A 2048 | Bf 1024 | Bc 1024 ] halfs = 128 KB total
    __shared__ __align__(16) _Float16 lS[4][NSTG][4096];
    __shared__ float x1s[BM];

    const int tid    = threadIdx.x;
    const int wid    = tid >> 6;
    const int lane   = tid & 63;
    const int lane15 = lane & 15;
    const int quad   = lane >> 4;
    const int u0     = blockIdx.x * BU;
    const int b0     = blockIdx.y * BM;
    const int wrow   = (wid >> 1) * 64;   // wave's A-row base
    const int wcol   = (wid & 1) * 32;    // wave's B-col base

    // ---- prologue: integrator state (loads used immediately; waits local) ----
    if (tid < BM) {
        const int b = b0 + tid;
        float x1n, x2n;
        if (t == 0) {
            x1n = x1_0[b];
            x2n = x2_0[b];
        } else {
            const int rd = (t + 1) & 1;
            const float x1p = x1w[rd * B_DIM + b];
            const float x2p = x2w[rd * B_DIM + b];
            const float yp  = y[((t + 2) % 3) * B_DIM + b];
            const float ip  = inputs[(size_t)(t - 1) * B_DIM + b];
            x1n = x1p + x2p;
            x2n = x2p + ip * yp;
        }
        x1s[tid] = x1n;
        if (blockIdx.x == 0) {
            const int wr = t & 1;
            x1w[wr * B_DIM + b] = x1n;
            x2w[wr * B_DIM + b] = x2n;
            if (t > 0) out[(size_t)(t - 1) * B_DIM + b] = x1n;
            y[((t + 1) % 3) * B_DIM + b] = 0.f;
        }
    }

    // ---- epilogue constants + h gate values to registers ----
    float kf[2], kc[2], bf_[2], bc_[2], ok_[2];
    #pragma unroll
    for (int nt = 0; nt < 2; ++nt) {
        const int u = u0 + wcol + nt * 16 + lane15;
        kf[nt] = kern[u];
        kc[nt] = kern[U_DIM + u];
        bf_[nt] = bias[u];
        bc_[nt] = bias[U_DIM + u];
        ok_[nt] = okern[u];
    }
    _Float16 hv[4][2][4];
    #pragma unroll
    for (int mt = 0; mt < 4; ++mt)
        #pragma unroll
        for (int nt = 0; nt < 2; ++nt)
            #pragma unroll
            for (int reg = 0; reg < 4; ++reg)
                hv[mt][nt][reg] = hA[(size_t)(b0 + wrow + mt * 16 + quad * 4 + reg) * U_DIM
                                     + u0 + wcol + nt * 16 + lane15];

    // ---- per-wave stage DMA: 8 x 1KB regions (A:4, Bf:2, Bc:2) ----
    const int srow  = lane >> 2;                       // 0..15
    const int schnk = ((lane & 3) ^ (srow & 3)) * 8;   // XOR-swizzled K-chunk
    auto stage = [&](int st, int kt) {
        const int k0 = kt * BK;
        #pragma unroll
        for (int j = 0; j < 4; ++j)
            async_cp16(hA + (size_t)(b0 + wrow + j * 16 + srow) * U_DIM + k0 + schnk,
                       &lS[wid][st][j * 512]);
        #pragma unroll
        for (int j = 0; j < 2; ++j) {
            async_cp16(Rt + (size_t)(u0 + wcol + j * 16 + srow) * U_DIM + k0 + schnk,
                       &lS[wid][st][2048 + j * 512]);
            async_cp16(Rt + (size_t)(U_DIM + u0 + wcol + j * 16 + srow) * U_DIM + k0 + schnk,
                       &lS[wid][st][3072 + j * 512]);
        }
    };
    stage(0, 0);
    stage(1, 1);
    stage(2, 2);

    f4 accF[4][2], accC[4][2];
    #pragma unroll
    for (int mt = 0; mt < 4; ++mt)
        #pragma unroll
        for (int nt = 0; nt < 2; ++nt) {
            accF[mt][nt] = (f4){0.f, 0.f, 0.f, 0.f};
            accC[mt][nt] = (f4){0.f, 0.f, 0.f, 0.f};
        }

    const int sw = (quad ^ (lane15 & 3)) * 8;
    auto body = [&](int kt) {
        const int st = kt & 3;
        h8 af[4], bff[2], bfc[2];
        #pragma unroll
        for (int mt = 0; mt < 4; ++mt)
            af[mt] = *(const h8*)&lS[wid][st][mt * 512 + lane15 * 32 + sw];
        #pragma unroll
        for (int nt = 0; nt < 2; ++nt) {
            bff[nt] = *(const h8*)&lS[wid][st][2048 + nt * 512 + lane15 * 32 + sw];
            bfc[nt] = *(const h8*)&lS[wid][st][3072 + nt * 512 + lane15 * 32 + sw];
        }
        #pragma unroll
        for (int mt = 0; mt < 4; ++mt)
            #pragma unroll
            for (int nt = 0; nt < 2; ++nt) {
                accF[mt][nt] = __builtin_amdgcn_mfma_f32_16x16x32_f16(af[mt], bff[nt], accF[mt][nt], 0, 0, 0);
                accC[mt][nt] = __builtin_amdgcn_mfma_f32_16x16x32_f16(af[mt], bfc[nt], accC[mt][nt], 0, 0, 0);
            }
    };

    // ---- barrier-free K-loop: self-paced vmcnt, stages ordered => exact ----
    for (int kt = 0; kt < KITERS - 2; ++kt) {
        __builtin_amdgcn_s_waitcnt(0x4F70);   // vmcnt(16): stage kt's 8 DMAs done
        body(kt);
        if (kt + 3 < KITERS) stage((kt + 3) & 3, kt + 3);
    }
    __builtin_amdgcn_s_waitcnt(0x0F78);       // vmcnt(8)
    body(KITERS - 2);
    __builtin_amdgcn_s_waitcnt(0x0F70);       // vmcnt(0)
    body(KITERS - 1);

    __syncthreads();   // all waves done with private stages; x1s visible; lC overlay safe

    // ---- epilogue: gates (h from regs); c -> lC overlay; y partials ----
    _Float16* lC = &lS[0][0][0];   // 128 x 72 halfs = 18 KB (inside waves0-1 region)
    float* ycur = y + (t % 3) * B_DIM;
    #pragma unroll
    for (int mt = 0; mt < 4; ++mt) {
        const int rlb = wrow + mt * 16 + quad * 4;
        float psum[4] = {0.f, 0.f, 0.f, 0.f};
        #pragma unroll
        for (int nt = 0; nt < 2; ++nt) {
            const int ul = wcol + nt * 16 + lane15;
            #pragma unroll
            for (int reg = 0; reg < 4; ++reg) {
                const int rl = rlb + reg;
                const float x1 = x1s[rl];
                const float xf = accF[mt][nt][reg] + x1 * kf[nt] + bf_[nt];
                const float xc = accC[mt][nt][reg] + x1 * kc[nt] + bc_[nt];
                const float fg = 1.f / (1.f + __expf(-xf));
                const float th = 1.f - 2.f / (1.f + __expf(2.f * xc));
                const float cv = fg * (float)hv[mt][nt][reg] + (1.f - fg) * th;
                lC[rl * 72 + ul] = (_Float16)cv;
                psum[reg] += cv * ok_[nt];
            }
        }
        #pragma unroll
        for (int reg = 0; reg < 4; ++reg) {
            float s = psum[reg];
            s += __shfl_xor(s, 1);
            s += __shfl_xor(s, 2);
            s += __shfl_xor(s, 4);
            s += __shfl_xor(s, 8);
            if (lane15 == 0) atomicAdd(&ycur[b0 + rlb + reg], s);
        }
    }

    // ---- coalesced c write-out ----
    __syncthreads();
    #pragma unroll
    for (int j = 0; j < 4; ++j) {
        const int idx = j * 256 + tid;     // 1024 uint4 = 128 rows x 8
        const int row = idx >> 3;
        const int col = idx & 7;
        *(uint4*)&hB[(size_t)(b0 + row) * U_DIM + u0 + col * 8] =
            *(const uint4*)&lC[row * 72 + col * 8];
    }
}

// ---------------- tail: out[T-1] = x1(T) ----------------
__global__ void finish(const float* __restrict__ x1w1, const float* __restrict__ x2w1,
                       float* __restrict__ out_last) {
    const int i = blockIdx.x * 256 + threadIdx.x;
    out_last[i] = x1w1[i] + x2w1[i];
}

// ---------------- host ----------------
extern "C" void kernel_launch(void* const* d_in, const int* in_sizes, int n_in,
                              void* d_out, int out_size, void* d_ws, size_t ws_size,
                              hipStream_t stream) {
    const float* inputs = (const float*)d_in[0];
    const float* x1_0   = (const float*)d_in[1];
    const float* x2_0   = (const float*)d_in[2];
    const float* c0     = (const float*)d_in[3];
    const float* kern   = (const float*)d_in[4];
    const float* rker   = (const float*)d_in[5];
    const float* bias   = (const float*)d_in[6];
    const float* okern  = (const float*)d_in[7];
    float* out = (float*)d_out;

    _Float16* Rt = (_Float16*)d_ws;                       // 4 MB
    _Float16* h0 = Rt + (size_t)2 * U_DIM * U_DIM;        // 4 MB
    _Float16* h1 = h0 + (size_t)B_DIM * U_DIM;            // 4 MB
    float* y   = (float*)(h1 + (size_t)B_DIM * U_DIM);    // 3*B
    float* x1w = y + 3 * B_DIM;                           // 2*B
    float* x2w = x1w + 2 * B_DIM;                         // 2*B

    transpose_R<<<dim3(64, 32), dim3(32, 8), 0, stream>>>(rker, Rt);
    init_state<<<dim3(B_DIM * U_DIM / 256), dim3(256), 0, stream>>>(c0, h0, y);

    _Float16* hcur = h0;
    _Float16* hnxt = h1;
    for (int t = 0; t < T_STEPS; ++t) {
        gemm_step<<<dim3(U_DIM / BU, B_DIM / BM), dim3(256), 0, stream>>>(
            hcur, hnxt, Rt, x1_0, x2_0, x1w, x2w, kern, bias, okern, y,
            inputs, out, t);
        _Float16* tmp = hcur; hcur = hnxt; hnxt = tmp;
    }
    finish<<<dim3(B_DIM / 256), dim3(256), 0, stream>>>(
        x1w + B_DIM, x2w + B_DIM, out + (size_t)(T_STEPS - 1) * B_DIM);
}